// Round 4
// baseline (61.304 us; speedup 1.0000x reference)
//
#include <hip/hip_runtime.h>
#include <hip/hip_bf16.h>

// Q8_0-style fused dequant + linear: y[32,11008] = x[32,4096] @ W^T + bias
// W[o,i] = (qweight[o,i] - 127) * scales[o, i/32]
//
// Round 4: LDS-free streaming MFMA, zero atomics.
//  k1: x (f32) -> bf16 into ws
//  k2: per-wave 16o x 32b tile, K-split x8; W dequantized in registers from
//      global (each weight read exactly once); chunked (64-k) double-buffered
//      register pipeline; partials stored plain to ws.
//  k3: out = bias + sum of 8 partials.

#define O_DIM  11008
#define I_DIM  4096
#define NB     128               // scale blocks per o-row
#define B_DIM  32
#define NSPLIT 8
#define KT     (I_DIM / NSPLIT)  // 512
#define NCH    (KT / 64)         // 8 chunks of 64 k (2 MFMA steps each)
#define PART_STRIDE (B_DIM * O_DIM)   // floats per split partial

typedef __attribute__((ext_vector_type(8))) short bf16x8;
typedef __attribute__((ext_vector_type(4))) float f32x4;

static __device__ __forceinline__ unsigned short f2bf(float f) {
    return __builtin_bit_cast(unsigned short, __float2bfloat16(f));
}

// ---- k1: x -> bf16 ----
__global__ __launch_bounds__(256) void convert_kernel(const float* __restrict__ x,
                                                      unsigned short* __restrict__ xbf) {
    const int gid = blockIdx.x * 256 + threadIdx.x;   // 128 blocks -> 32768 threads
    const float4 v = reinterpret_cast<const float4*>(x)[gid];
    ushort4 u;
    u.x = f2bf(v.x); u.y = f2bf(v.y); u.z = f2bf(v.z); u.w = f2bf(v.w);
    reinterpret_cast<ushort4*>(xbf)[gid] = u;
}

static __device__ __forceinline__ bf16x8 dequant8(const int4 qa, const int4 qb,
                                                  const float s) {
    const float c = -127.0f * s;
    bf16x8 v;
    v[0] = (short)f2bf(fmaf((float)qa.x, s, c));
    v[1] = (short)f2bf(fmaf((float)qa.y, s, c));
    v[2] = (short)f2bf(fmaf((float)qa.z, s, c));
    v[3] = (short)f2bf(fmaf((float)qa.w, s, c));
    v[4] = (short)f2bf(fmaf((float)qb.x, s, c));
    v[5] = (short)f2bf(fmaf((float)qb.y, s, c));
    v[6] = (short)f2bf(fmaf((float)qb.z, s, c));
    v[7] = (short)f2bf(fmaf((float)qb.w, s, c));
    return v;
}

// ---- k2: streaming dequant-MFMA GEMM, partials to ws ----
__global__ __launch_bounds__(256) void gemm_stream_kernel(const unsigned short* __restrict__ xbf,
                                                          const int*   __restrict__ qw,
                                                          const float* __restrict__ scales,
                                                          float*       __restrict__ part) {
    const int t    = threadIdx.x;
    const int wav  = t >> 6;
    const int lan  = t & 63;
    const int lrow = lan & 15;     // fragment row (o within wave tile / m row)
    const int lq   = lan >> 4;     // lane quarter -> k sub-offset

    const int o_base = blockIdx.x * 64 + wav * 16;  // 172 blocks x 4 waves
    const int k_base = blockIdx.y * KT;             // 8 K-splits
    const int o_row  = o_base + lrow;

    const int*            __restrict__ wq = qw  + o_row * I_DIM + k_base + lq * 8;
    const unsigned short* __restrict__ xa = xbf + lrow * I_DIM + k_base + lq * 8;

    // 16 scales for this row's K-split (one per 32-k step)
    float sc[16];
    {
        const float4* sp = reinterpret_cast<const float4*>(&scales[o_row * NB + (k_base >> 5)]);
#pragma unroll
        for (int j = 0; j < 4; ++j) {
            const float4 v = sp[j];
            sc[4 * j + 0] = v.x; sc[4 * j + 1] = v.y;
            sc[4 * j + 2] = v.z; sc[4 * j + 3] = v.w;
        }
    }

    f32x4 acc0 = {0.f, 0.f, 0.f, 0.f};   // m rows 0..15
    f32x4 acc1 = {0.f, 0.f, 0.f, 0.f};   // m rows 16..31

    // chunk = 64 k = 2 MFMA steps; double-buffered registers (named slots)
    int4   w0[4], w1[4];
    bf16x8 a0[4], a1[4];

#define LOAD_CHUNK(WB, AB, c)                                                   \
    {                                                                           \
        const int*            wp = wq + (c) * 64;                               \
        const unsigned short* xp = xa + (c) * 64;                               \
        WB[0] = *reinterpret_cast<const int4*>(wp);                             \
        WB[1] = *reinterpret_cast<const int4*>(wp + 4);                         \
        WB[2] = *reinterpret_cast<const int4*>(wp + 32);                        \
        WB[3] = *reinterpret_cast<const int4*>(wp + 36);                        \
        AB[0] = *reinterpret_cast<const bf16x8*>(xp);                           \
        AB[1] = *reinterpret_cast<const bf16x8*>(xp + 16 * I_DIM);              \
        AB[2] = *reinterpret_cast<const bf16x8*>(xp + 32);                      \
        AB[3] = *reinterpret_cast<const bf16x8*>(xp + 32 + 16 * I_DIM);         \
    }

#define CONSUME_CHUNK(WB, AB, c)                                                \
    {                                                                           \
        const bf16x8 bA = dequant8(WB[0], WB[1], sc[2 * (c)]);                  \
        acc0 = __builtin_amdgcn_mfma_f32_16x16x32_bf16(AB[0], bA, acc0, 0, 0, 0); \
        acc1 = __builtin_amdgcn_mfma_f32_16x16x32_bf16(AB[1], bA, acc1, 0, 0, 0); \
        const bf16x8 bB = dequant8(WB[2], WB[3], sc[2 * (c) + 1]);              \
        acc0 = __builtin_amdgcn_mfma_f32_16x16x32_bf16(AB[2], bB, acc0, 0, 0, 0); \
        acc1 = __builtin_amdgcn_mfma_f32_16x16x32_bf16(AB[3], bB, acc1, 0, 0, 0); \
    }

    LOAD_CHUNK(w0, a0, 0)
    LOAD_CHUNK(w1, a1, 1)

#pragma unroll
    for (int cc = 0; cc < NCH / 2; ++cc) {
        const int cA = 2 * cc;
        const int cB = 2 * cc + 1;
        CONSUME_CHUNK(w0, a0, cA)
        if (cA + 2 < NCH) LOAD_CHUNK(w0, a0, cA + 2)
        CONSUME_CHUNK(w1, a1, cB)
        if (cB + 2 < NCH) LOAD_CHUNK(w1, a1, cB + 2)
    }

#undef LOAD_CHUNK
#undef CONSUME_CHUNK

    // C/D layout: col = lane&15 (o), row = (lane>>4)*4 + reg (m)  [m89]
    float* pp = part + blockIdx.y * PART_STRIDE;
#pragma unroll
    for (int r = 0; r < 4; ++r) {
        const int m = lq * 4 + r;
        pp[m * O_DIM + o_row]        = acc0[r];
        pp[(m + 16) * O_DIM + o_row] = acc1[r];
    }
}

// ---- k3: out = bias + sum of partials ----
__global__ __launch_bounds__(256) void reduce_kernel(const float* __restrict__ part,
                                                     const float* __restrict__ bias,
                                                     float* __restrict__ out) {
    const int o = blockIdx.x * 256 + threadIdx.x;   // grid.x = 43
    const int m = blockIdx.y;                        // grid.y = 32
    float v = bias[o];
#pragma unroll
    for (int s = 0; s < NSPLIT; ++s)
        v += part[s * PART_STRIDE + m * O_DIM + o];
    out[m * O_DIM + o] = v;
}

extern "C" void kernel_launch(void* const* d_in, const int* in_sizes, int n_in,
                              void* d_out, int out_size, void* d_ws, size_t ws_size,
                              hipStream_t stream) {
    const float* x      = (const float*)d_in[0];
    const int*   qw     = (const int*)d_in[1];
    const float* scales = (const float*)d_in[2];
    const float* bias   = (const float*)d_in[3];
    float*       out    = (float*)d_out;

    unsigned short* xbf  = (unsigned short*)d_ws;
    float*          part = (float*)((char*)d_ws + 262144);   // after 256 KB xbf

    // k1: x -> bf16 (32x4096 = 131072 elems, 4 per thread)
    hipLaunchKernelGGL(convert_kernel, dim3(128), dim3(256), 0, stream, x, xbf);

    // k2: streaming GEMM, K-split x8, partials to ws (no atomics)
    hipLaunchKernelGGL(gemm_stream_kernel, dim3(O_DIM / 64, NSPLIT), dim3(256), 0, stream,
                       xbf, qw, scales, part);

    // k3: reduce partials + bias
    hipLaunchKernelGGL(reduce_kernel, dim3(O_DIM / 256, B_DIM), dim3(256), 0, stream,
                       part, bias, out);
}

// Round 5
// 47.143 us; speedup vs baseline: 1.3004x; 1.3004x over previous
//
#include <hip/hip_runtime.h>
#include <hip/hip_bf16.h>

// Q8_0-style fused dequant + linear: y[32,11008] = x[32,4096] @ W^T + bias
// W[o,i] = (qweight[o,i] - 127) * scales[o, i/32]
//
// Round 5: barrier-free W streaming + one-shot LDS x tile.
//  k1 (gemm): block = 64 o x full 32 b x k-split of 256.
//      - x slice (32x256) converted f32->bf16 and staged in swizzled LDS once;
//        single __syncthreads; k-loop has ZERO barriers and W-only VMEM.
//      - W read straight from global (each weight exactly once), dequantized
//        in registers, fed to mfma_16x16x32_bf16; 3-buffer chunk pipeline
//        keeps 2 chunks (8 KB) of HBM loads in flight per wave.
//      - grid is split-major: the 16 k-split blocks of an o-tile are adjacent
//        in dispatch -> concurrent readers cover contiguous 16 KB rows.
//  k2 (reduce): out = bias + sum of 16 partials (no atomics anywhere).

#define O_DIM  11008
#define I_DIM  4096
#define NB     128                // scale blocks per o-row
#define B_DIM  32
#define NSPLIT 16
#define KT     (I_DIM / NSPLIT)   // 256
#define PART_STRIDE (B_DIM * O_DIM)

typedef __attribute__((ext_vector_type(8))) short bf16x8;
typedef __attribute__((ext_vector_type(4))) float f32x4;

static __device__ __forceinline__ unsigned short f2bf(float f) {
    return __builtin_bit_cast(unsigned short, __float2bfloat16(f));
}

static __device__ __forceinline__ bf16x8 dequant8(const int4 qa, const int4 qb,
                                                  const float s) {
    const float c = -127.0f * s;
    bf16x8 v;
    v[0] = (short)f2bf(fmaf((float)qa.x, s, c));
    v[1] = (short)f2bf(fmaf((float)qa.y, s, c));
    v[2] = (short)f2bf(fmaf((float)qa.z, s, c));
    v[3] = (short)f2bf(fmaf((float)qa.w, s, c));
    v[4] = (short)f2bf(fmaf((float)qb.x, s, c));
    v[5] = (short)f2bf(fmaf((float)qb.y, s, c));
    v[6] = (short)f2bf(fmaf((float)qb.z, s, c));
    v[7] = (short)f2bf(fmaf((float)qb.w, s, c));
    return v;
}

__global__ __launch_bounds__(256) void gemm_kernel(const float* __restrict__ x,
                                                   const int*   __restrict__ qw,
                                                   const float* __restrict__ scales,
                                                   float*       __restrict__ part) {
    __shared__ unsigned short x_s[B_DIM * KT];   // 16 KB, XOR-swizzled

    const int t    = threadIdx.x;
    const int wav  = t >> 6;
    const int lan  = t & 63;
    const int lrow = lan & 15;      // fragment row
    const int lq   = lan >> 4;      // lane quarter -> k sub-offset

    const int split  = blockIdx.x;                    // fastest-varying: k-split
    const int k_base = split * KT;
    const int o_row  = blockIdx.y * 64 + wav * 16 + lrow;

    // ---- stage x once: f32 global -> bf16 swizzled LDS ----
    {
        const int m  = t >> 3;            // 0..31
        const int k0 = (t & 7) * 32;      // 0..224
        const float4* xv = reinterpret_cast<const float4*>(x + m * I_DIM + k_base + k0);
#pragma unroll
        for (int j = 0; j < 4; ++j) {
            const float4 va = xv[2 * j];
            const float4 vb = xv[2 * j + 1];
            bf16x8 v;
            v[0] = (short)f2bf(va.x); v[1] = (short)f2bf(va.y);
            v[2] = (short)f2bf(va.z); v[3] = (short)f2bf(va.w);
            v[4] = (short)f2bf(vb.x); v[5] = (short)f2bf(vb.y);
            v[6] = (short)f2bf(vb.z); v[7] = (short)f2bf(vb.w);
            const int addr = ((m * KT + k0 + j * 8) * 2) ^ ((m & 7) << 4);
            *reinterpret_cast<bf16x8*>(reinterpret_cast<char*>(x_s) + addr) = v;
        }
    }

    const int* __restrict__ wq = qw + o_row * I_DIM + k_base + lq * 8;

    // 8 scales for this row's k-split (one per 32-k step)
    float sc[8];
    {
        const float4* sp = reinterpret_cast<const float4*>(&scales[o_row * NB + split * 8]);
        const float4 s0 = sp[0], s1 = sp[1];
        sc[0] = s0.x; sc[1] = s0.y; sc[2] = s0.z; sc[3] = s0.w;
        sc[4] = s1.x; sc[5] = s1.y; sc[6] = s1.z; sc[7] = s1.w;
    }

    // chunk = 64 k (2 MFMA k-steps); lane's W slice = 2x 32B contiguous
    int4 wa0, wb0, wc0, wd0, wa1, wb1, wc1, wd1, wa2, wb2, wc2, wd2;

#define LOADW(A, B, C, D, c) {                         \
        const int* wp = wq + (c) * 64;                 \
        A = *reinterpret_cast<const int4*>(wp);        \
        B = *reinterpret_cast<const int4*>(wp + 4);    \
        C = *reinterpret_cast<const int4*>(wp + 32);   \
        D = *reinterpret_cast<const int4*>(wp + 36); }

    // issue first 2 chunks before the barrier (they don't touch LDS)
    LOADW(wa0, wb0, wc0, wd0, 0)
    LOADW(wa1, wb1, wc1, wd1, 1)

    __syncthreads();

    f32x4 acc0 = {0.f, 0.f, 0.f, 0.f};   // m rows 0..15
    f32x4 acc1 = {0.f, 0.f, 0.f, 0.f};   // m rows 16..31
    const int swz = (lrow & 7) << 4;

#define CONSUME(A, B, C, D, c) {                                                              \
        const int kb = (c) * 64 + lq * 8;                                                     \
        const bf16x8 a0 = *reinterpret_cast<const bf16x8*>(                                   \
            reinterpret_cast<const char*>(x_s) + ((( lrow       * KT + kb) * 2) ^ swz));      \
        const bf16x8 a1 = *reinterpret_cast<const bf16x8*>(                                   \
            reinterpret_cast<const char*>(x_s) + ((((lrow + 16) * KT + kb) * 2) ^ swz));      \
        const bf16x8 bA = dequant8(A, B, sc[2 * (c)]);                                        \
        acc0 = __builtin_amdgcn_mfma_f32_16x16x32_bf16(a0, bA, acc0, 0, 0, 0);                \
        acc1 = __builtin_amdgcn_mfma_f32_16x16x32_bf16(a1, bA, acc1, 0, 0, 0);                \
        const bf16x8 a2 = *reinterpret_cast<const bf16x8*>(                                   \
            reinterpret_cast<const char*>(x_s) + ((( lrow       * KT + kb + 32) * 2) ^ swz)); \
        const bf16x8 a3 = *reinterpret_cast<const bf16x8*>(                                   \
            reinterpret_cast<const char*>(x_s) + ((((lrow + 16) * KT + kb + 32) * 2) ^ swz)); \
        const bf16x8 bB = dequant8(C, D, sc[2 * (c) + 1]);                                    \
        acc0 = __builtin_amdgcn_mfma_f32_16x16x32_bf16(a2, bB, acc0, 0, 0, 0);                \
        acc1 = __builtin_amdgcn_mfma_f32_16x16x32_bf16(a3, bB, acc1, 0, 0, 0); }

    // 4 chunks, 3 buffers: consume c with chunks c+1, c+2 in flight
    LOADW(wa2, wb2, wc2, wd2, 2)
    CONSUME(wa0, wb0, wc0, wd0, 0)
    LOADW(wa0, wb0, wc0, wd0, 3)
    CONSUME(wa1, wb1, wc1, wd1, 1)
    CONSUME(wa2, wb2, wc2, wd2, 2)
    CONSUME(wa0, wb0, wc0, wd0, 3)

#undef LOADW
#undef CONSUME

    // C/D layout: col = lane&15 (o), row = (lane>>4)*4 + reg (m)  [m89]
    float* pp = part + split * PART_STRIDE;
#pragma unroll
    for (int r = 0; r < 4; ++r) {
        const int m = lq * 4 + r;
        pp[m * O_DIM + o_row]        = acc0[r];
        pp[(m + 16) * O_DIM + o_row] = acc1[r];
    }
}

// ---- k2: out = bias + sum of partials ----
__global__ __launch_bounds__(256) void reduce_kernel(const float* __restrict__ part,
                                                     const float* __restrict__ bias,
                                                     float* __restrict__ out) {
    const int o = blockIdx.x * 256 + threadIdx.x;   // grid.x = 43
    const int m = blockIdx.y;                        // grid.y = 32
    float v = bias[o];
#pragma unroll
    for (int s = 0; s < NSPLIT; ++s)
        v += part[s * PART_STRIDE + m * O_DIM + o];
    out[m * O_DIM + o] = v;
}

extern "C" void kernel_launch(void* const* d_in, const int* in_sizes, int n_in,
                              void* d_out, int out_size, void* d_ws, size_t ws_size,
                              hipStream_t stream) {
    const float* x      = (const float*)d_in[0];
    const int*   qw     = (const int*)d_in[1];
    const float* scales = (const float*)d_in[2];
    const float* bias   = (const float*)d_in[3];
    float*       out    = (float*)d_out;
    float*       part   = (float*)d_ws;              // 16 x 32 x 11008 f32 = 22.5 MB

    // k1: streaming dequant-MFMA GEMM, split-major dispatch
    hipLaunchKernelGGL(gemm_kernel, dim3(NSPLIT, O_DIM / 64), dim3(256), 0, stream,
                       x, qw, scales, part);

    // k2: reduce partials + bias
    hipLaunchKernelGGL(reduce_kernel, dim3(O_DIM / 256, B_DIM), dim3(256), 0, stream,
                       part, bias, out);
}